// Round 25
// baseline (165.475 us; speedup 1.0000x reference)
//
#include <hip/hip_runtime.h>
#include <math.h>

// Problem constants
#define DIM   384
#define NQKV  1152
#define IMG   56
#define ROWS_PER_B (IMG*IMG)           // 3136 pixels per batch image
#define TOTROWS (16*ROWS_PER_B)        // 50176

typedef unsigned short u16;
typedef unsigned int u32;
typedef __attribute__((ext_vector_type(2))) unsigned int u32x2;
typedef __attribute__((ext_vector_type(4))) float f32x4;
typedef __attribute__((ext_vector_type(8))) short s16x8;

__device__ __forceinline__ u16 f2b(float f) {           // fp32 -> bf16 RNE
    unsigned u = __float_as_uint(f);
    return (u16)((u + 0x7fffu + ((u >> 16) & 1u)) >> 16);
}

// async global->LDS, 16B/lane, dest = wave-uniform base + lane*16
__device__ __forceinline__ void gl2lds16(const void* g, void* l) {
    __builtin_amdgcn_global_load_lds(
        (const __attribute__((address_space(1))) void*)g,
        (__attribute__((address_space(3))) void*)l, 16, 0, 0);
}

// ---------------------------------------------------------------------------
// Setup megakernel (R22-verified, -11.6us): 5 prologue tasks, ONE dispatch.
// emb4 sinusoid math bit-faithful to numpy arange fill (verified R3) —
// delta = fl(fl(1+1/7)-1); x[i] = fl(1+fl(i*delta)); DO NOT TOUCH.
// ---------------------------------------------------------------------------
#define NB_CVT  18816                   // 50176*384/4 / 256, exact
#define NB_EMB  16
#define NB_WQ   1728
#define NB_WO   576
#define NB_BIAS 5
#define NB_SETUP (NB_CVT + NB_EMB + NB_WQ + NB_WO + NB_BIAS)

__global__ __launch_bounds__(256) void setup_kernel(
    const float* __restrict__ x, const float* __restrict__ w_qkv,
    const float* __restrict__ b_qkv, const float* __restrict__ w_out,
    float* __restrict__ emb4, u16* __restrict__ wqkvt,
    u16* __restrict__ woutt, float* __restrict__ bqkvp,
    u16* __restrict__ xb)
{
    const int bid = blockIdx.x;
    const int tid = threadIdx.x;

    if (bid < NB_CVT) {                               // ---- cvt x -> bf16 ----
        int i = bid * 256 + tid;                      // n4 = 4,816,896 exact
        float4 v = ((const float4*)x)[i];
        ushort4 o;
        o.x = f2b(v.x); o.y = f2b(v.y); o.z = f2b(v.z); o.w = f2b(v.w);
        ((ushort4*)xb)[i] = o;
        return;
    }
    if (bid < NB_CVT + NB_EMB) {                      // ---- emb4 table ----
        int idx = (bid - NB_CVT) * 256 + tid;
        if (idx >= 64 * 64) return;
        int q = idx >> 6, k = idx & 63;
        bool pad = (q >= 49) || (k >= 49);
        float base = 0.f;
        if (!pad) {
            const double step  = 1.0 / 7.0;
            const double delta = __dsub_rn(__dadd_rn(1.0, step), 1.0);
            double xk = __dadd_rn(1.0, __dmul_rn((double)k, delta));
            double xq = __dadd_rn(1.0, __dmul_rn((double)q, delta));
            int xi = (int)__dsub_rn(xk, xq);
            int yi = (k % 7) - (q % 7);
            int r = xi % 13; if (r < 0) r += 13;
            int c = yi % 13; if (c < 0) c += 13;
            const float scl = (float)(-0.7084877209212449);  // -log(1e4)/13
            if ((c & 1) == 0) base = sinf((float)r * expf((float)c * scl));
            else              base = cosf((float)r * expf((float)(c - 1) * scl));
        }
        bool rmask = !pad && ((q >= 28) != (k >= 28));
        bool cmask = !pad && ((q % 7 >= 4) != (k % 7 >= 4));
        #pragma unroll
        for (int v = 0; v < 4; ++v) {
            float val = base;
            if (pad || ((v & 1) && rmask) || ((v & 2) && cmask)) val = -INFINITY;
            emb4[v * 4096 + idx] = val;
        }
        return;
    }
    if (bid < NB_CVT + NB_EMB + NB_WQ) {              // ---- wqkv T+deint ----
        int i = (bid - NB_CVT - NB_EMB) * 256 + tid;
        if (i >= 384 * 1152) return;
        int k = i / 1152, col = i % 1152;
        int ch = col / 3, comp = col % 3;
        int np = comp * 384 + ch;
        wqkvt[(size_t)np * 384 + k] = f2b(w_qkv[i]);
        return;
    }
    if (bid < NB_CVT + NB_EMB + NB_WQ + NB_WO) {      // ---- wout T ----
        int i = (bid - NB_CVT - NB_EMB - NB_WQ) * 256 + tid;
        if (i >= 384 * 384) return;
        int r = i / 384, c = i % 384;
        woutt[(size_t)c * 384 + r] = f2b(w_out[i]);
        return;
    }
    {                                                 // ---- bias perm ----
        int n = (bid - NB_CVT - NB_EMB - NB_WQ - NB_WO) * 256 + tid;
        if (n >= 1152) return;
        int comp = n / 384, ch = n % 384;
        bqkvp[n] = b_qkv[ch * 3 + comp];
    }
}

// ---------------------------------------------------------------------------
// MFMA bf16 GEMM, compile-time N/K (R24), NEW: T14 async-split for B.
// R24 ledger audit: single-buffered B was staged AFTER barrier#2 of step t
// but required landed at the vmcnt at the TOP of t+1 — only ~150 cyc to
// cover 300-900 cyc latency -> ~6 exposed stalls/block (~25-30% of dur).
// Fix: load B(t+1) into REGISTERS at the top of step t (a full step of
// compute hides the latency), ds_write into Bs after barrier#2 (same slot
// where STAGE_B sat, off the critical path). Write addr Bs[row*64+lane*8]
// is byte-identical to the gl2lds dest -> swizzle preserved.
// vmcnt ledger: top of t: issue breg(t+1)[2] then STAGE_A(t+1)[2] ->
// vmcnt(4) leaves the 4 newest in flight, drains A(t) (+older B). lgkm(0)
// publishes my previous ds_writes before the barrier releases readers.
// ds_write waits on breg via compiler vmcnt (landed under compute).
// 128x128 tile, BK=64, 8 waves, 64x32 sub-tiles, 48KB LDS -> 3 blocks/CU.
// Rule-21 swizzle (0 conflicts); bijective XCD remap.
// MODE 0: bf16 out (QKV). MODE 1: fp32 out (final projection).
// ---------------------------------------------------------------------------
template <int MODE, int N, int K>
__global__ __launch_bounds__(512, 6) void mfma_gemm(
    const u16* __restrict__ A, const u16* __restrict__ Bt,
    const float* __restrict__ bias,
    u16* __restrict__ outb, float* __restrict__ outf)
{
    __shared__ __align__(16) u16 As[2][8192];   // [128][64] swizzled, dbuf
    __shared__ __align__(16) u16 Bs[8192];      // [128][64] swizzled, single

    const int tid  = threadIdx.x;
    const int lane = tid & 63;
    const int wid  = tid >> 6;                   // 0..7
    const int wr   = wid >> 2, wc = wid & 3;     // 64-row half, 32-col quarter
    const int l15  = lane & 15, l4 = lane >> 4;

    const int gx  = gridDim.x;
    const int nwg = gx * gridDim.y;
    int wg  = blockIdx.y * gx + blockIdx.x;
    int q8  = nwg >> 3, r8 = nwg & 7;
    int xcd = wg & 7, idx = wg >> 3;
    int nid = (xcd < r8 ? xcd * (q8 + 1) : r8 * (q8 + 1) + (xcd - r8) * q8) + idx;
    const int bm = nid / gx, bn = nid % gx;

    const int srow  = lane >> 3;                 // 0..7 within an issue
    const int sslot = (lane & 7) ^ srow;         // pre-swizzled source slot
    const u16* pA[2];
    const u16* pB[2];
    #pragma unroll
    for (int i = 0; i < 2; ++i) {
        pA[i] = A  + (size_t)(bm * 128 + wid * 16 + i * 8 + srow) * K + sslot * 8;
        pB[i] = Bt + (size_t)(bn * 128 + wid * 16 + i * 8 + srow) * K + sslot * 8;
    }

    f32x4 acc[4][2] = {};
    constexpr int NT = K >> 6;                    // BK = 64, compile-time

    // prologue: A(0) + B(0) via async gl2lds
    #pragma unroll
    for (int _i = 0; _i < 2; ++_i)
        gl2lds16(pA[_i], &As[0][(wid * 16 + _i * 8) * 64]);
    #pragma unroll
    for (int _i = 0; _i < 2; ++_i)
        gl2lds16(pB[_i], &Bs[(wid * 16 + _i * 8) * 64]);

    #pragma unroll
    for (int t = 0; t < NT; ++t) {
        const int buf = t & 1;
        s16x8 breg[2];
        if (t + 1 < NT) {
            const int _kt = (t + 1) << 6;
            #pragma unroll
            for (int _i = 0; _i < 2; ++_i)         // B(t+1) -> regs (issue early)
                breg[_i] = *(const s16x8*)(pB[_i] + _kt);
            __builtin_amdgcn_sched_barrier(0);
            #pragma unroll
            for (int _i = 0; _i < 2; ++_i)         // A(t+1) -> LDS (async)
                gl2lds16(pA[_i] + _kt, &As[buf ^ 1][(wid * 16 + _i * 8) * 64]);
            __builtin_amdgcn_sched_barrier(0);
            // drain A(t) (+ all older); leave {breg(t+1), A(t+1)} in flight.
            // lgkm(0) publishes my B ds_writes from step t-1 before barrier.
            asm volatile("s_waitcnt vmcnt(4) lgkmcnt(0)" ::: "memory");
        } else {
            asm volatile("s_waitcnt vmcnt(0) lgkmcnt(0)" ::: "memory");
        }
        __builtin_amdgcn_s_barrier();            // tile t fully visible
        __builtin_amdgcn_sched_barrier(0);

        #pragma unroll
        for (int kk = 0; kk < 2; ++kk) {
            s16x8 af[4], bf[2];
            #pragma unroll
            for (int m = 0; m < 4; ++m) {
                int rm = wr * 64 + m * 16 + l15;
                int sl = (kk * 4 + l4) ^ (rm & 7);
                af[m] = *(const s16x8*)&As[buf][rm * 64 + sl * 8];
            }
            #pragma unroll
            for (int n = 0; n < 2; ++n) {
                int rn = wc * 32 + n * 16 + l15;
                int sl = (kk * 4 + l4) ^ (rn & 7);
                bf[n] = *(const s16x8*)&Bs[rn * 64 + sl * 8];
            }
            #pragma unroll
            for (int m = 0; m < 4; ++m)
                #pragma unroll
                for (int n = 0; n < 2; ++n)
                    acc[m][n] = __builtin_amdgcn_mfma_f32_16x16x32_bf16(
                        af[m], bf[n], acc[m][n], 0, 0, 0);
        }

        if (t + 1 < NT) {
            asm volatile("s_waitcnt lgkmcnt(0)" ::: "memory");  // B reads done
            __builtin_amdgcn_sched_barrier(0);
            __builtin_amdgcn_s_barrier();        // all waves' reads retired
            // write-late: B(t+1) regs -> Bs (off critical path; regs landed
            // under this step's compute; published at next top's lgkm(0))
            #pragma unroll
            for (int _i = 0; _i < 2; ++_i)
                *(s16x8*)&Bs[(wid * 16 + _i * 8) * 64 + lane * 8] = breg[_i];
        }
    }

    const int grow0 = bm * 128 + wr * 64;
    const int gcol0 = bn * 128 + wc * 32;
    #pragma unroll
    for (int m = 0; m < 4; ++m) {
        #pragma unroll
        for (int n = 0; n < 2; ++n) {
            int col = gcol0 + n * 16 + l15;
            float bz = bias[col];
            #pragma unroll
            for (int r = 0; r < 4; ++r) {
                int row = grow0 + m * 16 + l4 * 4 + r;
                float v = acc[m][n][r] + bz;
                if constexpr (MODE == 0)
                    outb[(size_t)row * N + col] = f2b(v);
                else
                    outf[(size_t)row * N + col] = v;
            }
        }
    }
}

// ---------------------------------------------------------------------------
// Kernel 3: MFMA windowed attention (R20-verified): stageless, T5 setprio,
// T14 issue-early V, emb software-pipeline, b64 P writes. Unchanged.
// ---------------------------------------------------------------------------
__global__ __launch_bounds__(256) void attn_mfma_kernel(
    const u16* __restrict__ qkv, const float* __restrict__ emb4,
    u16* __restrict__ att)
{
    __shared__ __align__(16) u16 P4[4][64 * 72];   // 36864 B
    __shared__ int rowIn[64];
    __shared__ int rowOut[64];

    const int tid  = threadIdx.x;
    const int lane = tid & 63;
    const int wid  = tid >> 6;
    const int l15  = lane & 15, l4 = lane >> 4;

    const int blk = blockIdx.x;
    const int hg  = blk % 3;
    const int win = (blk / 3) & 63;
    const int b   = blk / 192;
    const int bw  = win & 7, bh = win >> 3;
    const int head = hg * 4 + wid;

    if (tid < 64) {                                 // roll(-4,-4) gather LUT
        int pix = tid;
        int gr = (bh * 7 + pix / 7 + 4) % IMG;
        int gc = (bw * 7 + pix % 7 + 4) % IMG;
        rowIn[pix] = (b * IMG + gr) * IMG + gc;
    } else if (tid < 128) {                         // roll(+3,+3) scatter LUT
        int q = tid - 64;
        int fr = (bh * 7 + q / 7 + 3) % IMG;
        int fc = (bw * 7 + q % 7 + 3) % IMG;
        rowOut[q] = (b * IMG + fr) * IMG + fc;
    }
    __syncthreads();

    // ---- issue ALL global loads up front (Q, K fragments + V fragments) ----
    s16x8 qf[4], kf[4];
    #pragma unroll
    for (int n = 0; n < 4; ++n) {
        int pix = n * 16 + l15;
        size_t base = (size_t)rowIn[pix] * NQKV + head * 32 + l4 * 8;
        qf[n] = *(const s16x8*)(qkv + base);          // Q
        kf[n] = *(const s16x8*)(qkv + base + 384);    // K
    }
    s16x8 vf[2][2];                                   // [kh][ne]
    #pragma unroll
    for (int kh = 0; kh < 2; ++kh)
        #pragma unroll
        for (int ne = 0; ne < 2; ++ne)
            #pragma unroll
            for (int j = 0; j < 8; ++j) {
                int pix = kh * 32 + l4 * 8 + j;
                vf[kh][ne][j] = (short)qkv[(size_t)rowIn[pix] * NQKV + 768
                                           + head * 32 + ne * 16 + l15];
            }

    const float* ev = emb4 + ((bh == 7 ? 1 : 0) + (bw == 7 ? 2 : 0)) * 4096;

    float4 ecur[4], enxt[4];
    #pragma unroll
    for (int m = 0; m < 4; ++m)
        ecur[m] = *(const float4*)(ev + (size_t)l15 * 64 + m * 16 + l4 * 4);

    f32x4 sc[4][4] = {};
    __builtin_amdgcn_s_setprio(1);
    #pragma unroll
    for (int m = 0; m < 4; ++m)
        #pragma unroll
        for (int n = 0; n < 4; ++n)
            sc[m][n] = __builtin_amdgcn_mfma_f32_16x16x32_bf16(
                kf[m], qf[n], sc[m][n], 0, 0, 0);
    __builtin_amdgcn_s_setprio(0);

    const float scale = 0.17677669529663687f;        // 1/sqrt(32)
    u16* P = P4[wid];
    u32* P32 = (u32*)P;

    #pragma unroll
    for (int n = 0; n < 4; ++n) {
        if (n < 3) {
            #pragma unroll
            for (int m = 0; m < 4; ++m)
                enxt[m] = *(const float4*)(ev + (size_t)((n + 1) * 16 + l15) * 64
                                           + m * 16 + l4 * 4);
        }
        const int q = n * 16 + l15;
        float vals[4][4];
        float mx = -INFINITY;
        #pragma unroll
        for (int m = 0; m < 4; ++m) {
            #pragma unroll
            for (int r = 0; r < 4; ++r) {
                float v = sc[m][n][r] * scale + ((const float*)&ecur[m])[r];
                vals[m][r] = v;
                mx = fmaxf(mx, v);
            }
        }
        mx = fmaxf(mx, __shfl_xor(mx, 16));
        mx = fmaxf(mx, __shfl_xor(mx, 32));
        float sum = 0.f;
        #pragma unroll
        for (int m = 0; m < 4; ++m)
            #pragma unroll
            for (int r = 0; r < 4; ++r) {
                float p = __expf(vals[m][r] - mx);
                vals[m][r] = p;
                sum += p;
            }
        sum += __shfl_xor(sum, 16);
        sum += __shfl_xor(sum, 32);
        float inv = 1.f / sum;
        #pragma unroll
        for (int m = 0; m < 4; ++m) {
            u32x2 w;
            w[0] = (u32)f2b(vals[m][0] * inv) | ((u32)f2b(vals[m][1] * inv) << 16);
            w[1] = (u32)f2b(vals[m][2] * inv) | ((u32)f2b(vals[m][3] * inv) << 16);
            int bidx = q * 36 + m * 8 + l4 * 2;
            *(u32x2*)&P32[bidx] = w;
        }
        #pragma unroll
        for (int m = 0; m < 4; ++m) ecur[m] = enxt[m];
    }
    // per-wave private LDS RAW: compiler inserts lgkmcnt waits; no barrier.

    f32x4 o[4][2] = {};
    #pragma unroll
    for (int kh = 0; kh < 2; ++kh) {
        s16x8 pf[4];
        #pragma unroll
        for (int mq = 0; mq < 4; ++mq)
            pf[mq] = *(const s16x8*)&P[(mq * 16 + l15) * 72 + kh * 32 + l4 * 8];
        __builtin_amdgcn_s_setprio(1);
        #pragma unroll
        for (int mq = 0; mq < 4; ++mq)
            #pragma unroll
            for (int ne = 0; ne < 2; ++ne)
                o[mq][ne] = __builtin_amdgcn_mfma_f32_16x16x32_bf16(
                    pf[mq], vf[kh][ne], o[mq][ne], 0, 0, 0);
        __builtin_amdgcn_s_setprio(0);
    }

    #pragma unroll
    for (int mq = 0; mq < 4; ++mq) {
        #pragma unroll
        for (int r = 0; r < 4; ++r) {
            int q = mq * 16 + l4 * 4 + r;
            if (q < 49) {
                size_t rowb = (size_t)rowOut[q] * DIM + head * 32;
                #pragma unroll
                for (int ne = 0; ne < 2; ++ne)
                    att[rowb + ne * 16 + l15] = f2b(o[mq][ne][r]);
            }
        }
    }
}

// ---------------------------------------------------------------------------
extern "C" void kernel_launch(void* const* d_in, const int* in_sizes, int n_in,
                              void* d_out, int out_size, void* d_ws, size_t ws_size,
                              hipStream_t stream) {
    const float* x     = (const float*)d_in[0];
    const float* w_qkv = (const float*)d_in[1];
    const float* b_qkv = (const float*)d_in[2];
    const float* w_out = (const float*)d_in[3];
    const float* b_out = (const float*)d_in[4];
    float* out = (float*)d_out;

    char* wsp = (char*)d_ws;
    float* emb4  = (float*)wsp;                                  // 64 KB
    u16*   wqkvt = (u16*)(wsp + 65536);                          // [1152][384]
    u16*   woutt = (u16*)(wsp + 65536 + 884736);                 // [384][384]
    float* bqkvp = (float*)(wsp + 65536 + 884736 + 294912);      // [1152]
    u16*   xb    = (u16*)(wsp + 65536 + 884736 + 294912 + 4608); // full 38.5MB
    const size_t fixed = 65536 + 884736 + 294912 + 4608
                       + (size_t)TOTROWS * DIM * 2;              // 39,784,960 B

    // per-batch chunk bytes: qkv (bf16) + att (bf16)
    const size_t perb = (size_t)ROWS_PER_B * (NQKV + DIM) * 2;   // 9,633,792
    int nb = 16;
    while (nb > 2 && fixed + (size_t)nb * perb > ws_size) nb >>= 1;

    u16* qkvb = xb + (size_t)TOTROWS * DIM;
    u16* attb = qkvb + (size_t)nb * ROWS_PER_B * NQKV;

    // ONE setup dispatch: cvt(full x) + emb4 + both weight transposes + bias
    setup_kernel<<<NB_SETUP, 256, 0, stream>>>(
        x, w_qkv, b_qkv, w_out, emb4, wqkvt, woutt, bqkvp, xb);

    for (int b0 = 0; b0 < 16; b0 += nb) {
        const int rows = nb * ROWS_PER_B;
        const u16* xa = xb + (size_t)b0 * ROWS_PER_B * DIM;

        mfma_gemm<0, NQKV, DIM><<<dim3(NQKV / 128, rows / 128), 512, 0, stream>>>(
            xa, wqkvt, bqkvp, qkvb, nullptr);

        attn_mfma_kernel<<<nb * 192, 256, 0, stream>>>(qkvb, emb4, attb);

        mfma_gemm<1, DIM, DIM><<<dim3(DIM / 128, rows / 128), 512, 0, stream>>>(
            attb, woutt, b_out, nullptr, out + (size_t)b0 * ROWS_PER_B * DIM);
    }
}

// Round 26
// 151.173 us; speedup vs baseline: 1.0946x; 1.0946x over previous
//
#include <hip/hip_runtime.h>
#include <math.h>

// Problem constants
#define DIM   384
#define NQKV  1152
#define IMG   56
#define ROWS_PER_B (IMG*IMG)           // 3136 pixels per batch image
#define TOTROWS (16*ROWS_PER_B)        // 50176

typedef unsigned short u16;
typedef unsigned int u32;
typedef __attribute__((ext_vector_type(2))) unsigned int u32x2;
typedef __attribute__((ext_vector_type(4))) float f32x4;
typedef __attribute__((ext_vector_type(8))) short s16x8;

__device__ __forceinline__ u16 f2b(float f) {           // fp32 -> bf16 RNE
    unsigned u = __float_as_uint(f);
    return (u16)((u + 0x7fffu + ((u >> 16) & 1u)) >> 16);
}

// async global->LDS, 16B/lane, dest = wave-uniform base + lane*16
__device__ __forceinline__ void gl2lds16(const void* g, void* l) {
    __builtin_amdgcn_global_load_lds(
        (const __attribute__((address_space(1))) void*)g,
        (__attribute__((address_space(3))) void*)l, 16, 0, 0);
}

// ---------------------------------------------------------------------------
// Setup megakernel (R22-verified, -11.6us): 5 prologue tasks, ONE dispatch.
// emb4 sinusoid math bit-faithful to numpy arange fill (verified R3) —
// delta = fl(fl(1+1/7)-1); x[i] = fl(1+fl(i*delta)); DO NOT TOUCH.
// ---------------------------------------------------------------------------
#define NB_CVT  18816                   // 50176*384/4 / 256, exact
#define NB_EMB  16
#define NB_WQ   1728
#define NB_WO   576
#define NB_BIAS 5
#define NB_SETUP (NB_CVT + NB_EMB + NB_WQ + NB_WO + NB_BIAS)

__global__ __launch_bounds__(256) void setup_kernel(
    const float* __restrict__ x, const float* __restrict__ w_qkv,
    const float* __restrict__ b_qkv, const float* __restrict__ w_out,
    float* __restrict__ emb4, u16* __restrict__ wqkvt,
    u16* __restrict__ woutt, float* __restrict__ bqkvp,
    u16* __restrict__ xb)
{
    const int bid = blockIdx.x;
    const int tid = threadIdx.x;

    if (bid < NB_CVT) {                               // ---- cvt x -> bf16 ----
        int i = bid * 256 + tid;                      // n4 = 4,816,896 exact
        float4 v = ((const float4*)x)[i];
        ushort4 o;
        o.x = f2b(v.x); o.y = f2b(v.y); o.z = f2b(v.z); o.w = f2b(v.w);
        ((ushort4*)xb)[i] = o;
        return;
    }
    if (bid < NB_CVT + NB_EMB) {                      // ---- emb4 table ----
        int idx = (bid - NB_CVT) * 256 + tid;
        if (idx >= 64 * 64) return;
        int q = idx >> 6, k = idx & 63;
        bool pad = (q >= 49) || (k >= 49);
        float base = 0.f;
        if (!pad) {
            const double step  = 1.0 / 7.0;
            const double delta = __dsub_rn(__dadd_rn(1.0, step), 1.0);
            double xk = __dadd_rn(1.0, __dmul_rn((double)k, delta));
            double xq = __dadd_rn(1.0, __dmul_rn((double)q, delta));
            int xi = (int)__dsub_rn(xk, xq);
            int yi = (k % 7) - (q % 7);
            int r = xi % 13; if (r < 0) r += 13;
            int c = yi % 13; if (c < 0) c += 13;
            const float scl = (float)(-0.7084877209212449);  // -log(1e4)/13
            if ((c & 1) == 0) base = sinf((float)r * expf((float)c * scl));
            else              base = cosf((float)r * expf((float)(c - 1) * scl));
        }
        bool rmask = !pad && ((q >= 28) != (k >= 28));
        bool cmask = !pad && ((q % 7 >= 4) != (k % 7 >= 4));
        #pragma unroll
        for (int v = 0; v < 4; ++v) {
            float val = base;
            if (pad || ((v & 1) && rmask) || ((v & 2) && cmask)) val = -INFINITY;
            emb4[v * 4096 + idx] = val;
        }
        return;
    }
    if (bid < NB_CVT + NB_EMB + NB_WQ) {              // ---- wqkv T+deint ----
        int i = (bid - NB_CVT - NB_EMB) * 256 + tid;
        if (i >= 384 * 1152) return;
        int k = i / 1152, col = i % 1152;
        int ch = col / 3, comp = col % 3;
        int np = comp * 384 + ch;
        wqkvt[(size_t)np * 384 + k] = f2b(w_qkv[i]);
        return;
    }
    if (bid < NB_CVT + NB_EMB + NB_WQ + NB_WO) {      // ---- wout T ----
        int i = (bid - NB_CVT - NB_EMB - NB_WQ) * 256 + tid;
        if (i >= 384 * 384) return;
        int r = i / 384, c = i % 384;
        woutt[(size_t)c * 384 + r] = f2b(w_out[i]);
        return;
    }
    {                                                 // ---- bias perm ----
        int n = (bid - NB_CVT - NB_EMB - NB_WQ - NB_WO) * 256 + tid;
        if (n >= 1152) return;
        int comp = n / 384, ch = n % 384;
        bqkvp[n] = b_qkv[ch * 3 + comp];
    }
}

// ---------------------------------------------------------------------------
// MFMA bf16 GEMM (R24-EXACT restore — best measured config, total 151.27us).
// Compile-time N/K: NT=K/64=6 fully unrolled (buffer parity, stage offsets,
// tail branches static; VALUBusy 38->24 measured R24).
// 128x128 tile, BK=64, 8 waves, wave sub-tile 64x32; A dbuf + B single
// (48KB -> 3 blocks/CU = 24 waves/CU); vmcnt(2) counted ledger; rule-21
// both-sides swizzle (0 conflicts); bijective XCD remap.
// GEMM ledger closed: BK=64(+), 8-wave(+), template-K(+), XCD(+), swizzle(+);
// BM=256(-), 2-deep ring(0), single-barrier(0), cvt-fusion x3(-), reg-B(-).
// MODE 0: bf16 out (QKV). MODE 1: fp32 out (final projection).
// ---------------------------------------------------------------------------
template <int MODE, int N, int K>
__global__ __launch_bounds__(512, 6) void mfma_gemm(
    const u16* __restrict__ A, const u16* __restrict__ Bt,
    const float* __restrict__ bias,
    u16* __restrict__ outb, float* __restrict__ outf)
{
    __shared__ __align__(16) u16 As[2][8192];   // [128][64] swizzled, dbuf
    __shared__ __align__(16) u16 Bs[8192];      // [128][64] swizzled, single

    const int tid  = threadIdx.x;
    const int lane = tid & 63;
    const int wid  = tid >> 6;                   // 0..7
    const int wr   = wid >> 2, wc = wid & 3;     // 64-row half, 32-col quarter
    const int l15  = lane & 15, l4 = lane >> 4;

    const int gx  = gridDim.x;
    const int nwg = gx * gridDim.y;
    int wg  = blockIdx.y * gx + blockIdx.x;
    int q8  = nwg >> 3, r8 = nwg & 7;
    int xcd = wg & 7, idx = wg >> 3;
    int nid = (xcd < r8 ? xcd * (q8 + 1) : r8 * (q8 + 1) + (xcd - r8) * q8) + idx;
    const int bm = nid / gx, bn = nid % gx;

    const int srow  = lane >> 3;                 // 0..7 within an issue
    const int sslot = (lane & 7) ^ srow;         // pre-swizzled source slot
    const u16* pA[2];
    const u16* pB[2];
    #pragma unroll
    for (int i = 0; i < 2; ++i) {
        pA[i] = A  + (size_t)(bm * 128 + wid * 16 + i * 8 + srow) * K + sslot * 8;
        pB[i] = Bt + (size_t)(bn * 128 + wid * 16 + i * 8 + srow) * K + sslot * 8;
    }

    f32x4 acc[4][2] = {};
    constexpr int NT = K >> 6;                    // BK = 64, compile-time

    // prologue: A(0) + B(0) via async gl2lds
    #pragma unroll
    for (int _i = 0; _i < 2; ++_i)
        gl2lds16(pA[_i], &As[0][(wid * 16 + _i * 8) * 64]);
    #pragma unroll
    for (int _i = 0; _i < 2; ++_i)
        gl2lds16(pB[_i], &Bs[(wid * 16 + _i * 8) * 64]);

    #pragma unroll
    for (int t = 0; t < NT; ++t) {
        const int buf = t & 1;                    // compile-time under unroll
        if (t + 1 < NT) {
            const int _kt = (t + 1) << 6;
            #pragma unroll
            for (int _i = 0; _i < 2; ++_i)
                gl2lds16(pA[_i] + _kt, &As[buf ^ 1][(wid * 16 + _i * 8) * 64]);
            asm volatile("s_waitcnt vmcnt(2)" ::: "memory");
        } else {
            asm volatile("s_waitcnt vmcnt(0)" ::: "memory");
        }
        __builtin_amdgcn_s_barrier();
        __builtin_amdgcn_sched_barrier(0);

        #pragma unroll
        for (int kk = 0; kk < 2; ++kk) {
            s16x8 af[4], bf[2];
            #pragma unroll
            for (int m = 0; m < 4; ++m) {
                int rm = wr * 64 + m * 16 + l15;
                int sl = (kk * 4 + l4) ^ (rm & 7);
                af[m] = *(const s16x8*)&As[buf][rm * 64 + sl * 8];
            }
            #pragma unroll
            for (int n = 0; n < 2; ++n) {
                int rn = wc * 32 + n * 16 + l15;
                int sl = (kk * 4 + l4) ^ (rn & 7);
                bf[n] = *(const s16x8*)&Bs[rn * 64 + sl * 8];
            }
            #pragma unroll
            for (int m = 0; m < 4; ++m)
                #pragma unroll
                for (int n = 0; n < 2; ++n)
                    acc[m][n] = __builtin_amdgcn_mfma_f32_16x16x32_bf16(
                        af[m], bf[n], acc[m][n], 0, 0, 0);
        }

        if (t + 1 < NT) {
            asm volatile("s_waitcnt lgkmcnt(0)" ::: "memory");
            __builtin_amdgcn_sched_barrier(0);
            __builtin_amdgcn_s_barrier();
            const int _kt = (t + 1) << 6;
            #pragma unroll
            for (int _i = 0; _i < 2; ++_i)
                gl2lds16(pB[_i] + _kt, &Bs[(wid * 16 + _i * 8) * 64]);
        }
    }

    const int grow0 = bm * 128 + wr * 64;
    const int gcol0 = bn * 128 + wc * 32;
    #pragma unroll
    for (int m = 0; m < 4; ++m) {
        #pragma unroll
        for (int n = 0; n < 2; ++n) {
            int col = gcol0 + n * 16 + l15;
            float bz = bias[col];
            #pragma unroll
            for (int r = 0; r < 4; ++r) {
                int row = grow0 + m * 16 + l4 * 4 + r;
                float v = acc[m][n][r] + bz;
                if constexpr (MODE == 0)
                    outb[(size_t)row * N + col] = f2b(v);
                else
                    outf[(size_t)row * N + col] = v;
            }
        }
    }
}

// ---------------------------------------------------------------------------
// Kernel 3: MFMA windowed attention (R20-verified): stageless, T5 setprio,
// T14 issue-early V, emb software-pipeline, b64 P writes. Unchanged.
// ---------------------------------------------------------------------------
__global__ __launch_bounds__(256) void attn_mfma_kernel(
    const u16* __restrict__ qkv, const float* __restrict__ emb4,
    u16* __restrict__ att)
{
    __shared__ __align__(16) u16 P4[4][64 * 72];   // 36864 B
    __shared__ int rowIn[64];
    __shared__ int rowOut[64];

    const int tid  = threadIdx.x;
    const int lane = tid & 63;
    const int wid  = tid >> 6;
    const int l15  = lane & 15, l4 = lane >> 4;

    const int blk = blockIdx.x;
    const int hg  = blk % 3;
    const int win = (blk / 3) & 63;
    const int b   = blk / 192;
    const int bw  = win & 7, bh = win >> 3;
    const int head = hg * 4 + wid;

    if (tid < 64) {                                 // roll(-4,-4) gather LUT
        int pix = tid;
        int gr = (bh * 7 + pix / 7 + 4) % IMG;
        int gc = (bw * 7 + pix % 7 + 4) % IMG;
        rowIn[pix] = (b * IMG + gr) * IMG + gc;
    } else if (tid < 128) {                         // roll(+3,+3) scatter LUT
        int q = tid - 64;
        int fr = (bh * 7 + q / 7 + 3) % IMG;
        int fc = (bw * 7 + q % 7 + 3) % IMG;
        rowOut[q] = (b * IMG + fr) * IMG + fc;
    }
    __syncthreads();

    // ---- issue ALL global loads up front (Q, K fragments + V fragments) ----
    s16x8 qf[4], kf[4];
    #pragma unroll
    for (int n = 0; n < 4; ++n) {
        int pix = n * 16 + l15;
        size_t base = (size_t)rowIn[pix] * NQKV + head * 32 + l4 * 8;
        qf[n] = *(const s16x8*)(qkv + base);          // Q
        kf[n] = *(const s16x8*)(qkv + base + 384);    // K
    }
    s16x8 vf[2][2];                                   // [kh][ne]
    #pragma unroll
    for (int kh = 0; kh < 2; ++kh)
        #pragma unroll
        for (int ne = 0; ne < 2; ++ne)
            #pragma unroll
            for (int j = 0; j < 8; ++j) {
                int pix = kh * 32 + l4 * 8 + j;
                vf[kh][ne][j] = (short)qkv[(size_t)rowIn[pix] * NQKV + 768
                                           + head * 32 + ne * 16 + l15];
            }

    const float* ev = emb4 + ((bh == 7 ? 1 : 0) + (bw == 7 ? 2 : 0)) * 4096;

    float4 ecur[4], enxt[4];
    #pragma unroll
    for (int m = 0; m < 4; ++m)
        ecur[m] = *(const float4*)(ev + (size_t)l15 * 64 + m * 16 + l4 * 4);

    f32x4 sc[4][4] = {};
    __builtin_amdgcn_s_setprio(1);
    #pragma unroll
    for (int m = 0; m < 4; ++m)
        #pragma unroll
        for (int n = 0; n < 4; ++n)
            sc[m][n] = __builtin_amdgcn_mfma_f32_16x16x32_bf16(
                kf[m], qf[n], sc[m][n], 0, 0, 0);
    __builtin_amdgcn_s_setprio(0);

    const float scale = 0.17677669529663687f;        // 1/sqrt(32)
    u16* P = P4[wid];
    u32* P32 = (u32*)P;

    #pragma unroll
    for (int n = 0; n < 4; ++n) {
        if (n < 3) {
            #pragma unroll
            for (int m = 0; m < 4; ++m)
                enxt[m] = *(const float4*)(ev + (size_t)((n + 1) * 16 + l15) * 64
                                           + m * 16 + l4 * 4);
        }
        const int q = n * 16 + l15;
        float vals[4][4];
        float mx = -INFINITY;
        #pragma unroll
        for (int m = 0; m < 4; ++m) {
            #pragma unroll
            for (int r = 0; r < 4; ++r) {
                float v = sc[m][n][r] * scale + ((const float*)&ecur[m])[r];
                vals[m][r] = v;
                mx = fmaxf(mx, v);
            }
        }
        mx = fmaxf(mx, __shfl_xor(mx, 16));
        mx = fmaxf(mx, __shfl_xor(mx, 32));
        float sum = 0.f;
        #pragma unroll
        for (int m = 0; m < 4; ++m)
            #pragma unroll
            for (int r = 0; r < 4; ++r) {
                float p = __expf(vals[m][r] - mx);
                vals[m][r] = p;
                sum += p;
            }
        sum += __shfl_xor(sum, 16);
        sum += __shfl_xor(sum, 32);
        float inv = 1.f / sum;
        #pragma unroll
        for (int m = 0; m < 4; ++m) {
            u32x2 w;
            w[0] = (u32)f2b(vals[m][0] * inv) | ((u32)f2b(vals[m][1] * inv) << 16);
            w[1] = (u32)f2b(vals[m][2] * inv) | ((u32)f2b(vals[m][3] * inv) << 16);
            int bidx = q * 36 + m * 8 + l4 * 2;
            *(u32x2*)&P32[bidx] = w;
        }
        #pragma unroll
        for (int m = 0; m < 4; ++m) ecur[m] = enxt[m];
    }
    // per-wave private LDS RAW: compiler inserts lgkmcnt waits; no barrier.

    f32x4 o[4][2] = {};
    #pragma unroll
    for (int kh = 0; kh < 2; ++kh) {
        s16x8 pf[4];
        #pragma unroll
        for (int mq = 0; mq < 4; ++mq)
            pf[mq] = *(const s16x8*)&P[(mq * 16 + l15) * 72 + kh * 32 + l4 * 8];
        __builtin_amdgcn_s_setprio(1);
        #pragma unroll
        for (int mq = 0; mq < 4; ++mq)
            #pragma unroll
            for (int ne = 0; ne < 2; ++ne)
                o[mq][ne] = __builtin_amdgcn_mfma_f32_16x16x32_bf16(
                    pf[mq], vf[kh][ne], o[mq][ne], 0, 0, 0);
        __builtin_amdgcn_s_setprio(0);
    }

    #pragma unroll
    for (int mq = 0; mq < 4; ++mq) {
        #pragma unroll
        for (int r = 0; r < 4; ++r) {
            int q = mq * 16 + l4 * 4 + r;
            if (q < 49) {
                size_t rowb = (size_t)rowOut[q] * DIM + head * 32;
                #pragma unroll
                for (int ne = 0; ne < 2; ++ne)
                    att[rowb + ne * 16 + l15] = f2b(o[mq][ne][r]);
            }
        }
    }
}

// ---------------------------------------------------------------------------
extern "C" void kernel_launch(void* const* d_in, const int* in_sizes, int n_in,
                              void* d_out, int out_size, void* d_ws, size_t ws_size,
                              hipStream_t stream) {
    const float* x     = (const float*)d_in[0];
    const float* w_qkv = (const float*)d_in[1];
    const float* b_qkv = (const float*)d_in[2];
    const float* w_out = (const float*)d_in[3];
    const float* b_out = (const float*)d_in[4];
    float* out = (float*)d_out;

    char* wsp = (char*)d_ws;
    float* emb4  = (float*)wsp;                                  // 64 KB
    u16*   wqkvt = (u16*)(wsp + 65536);                          // [1152][384]
    u16*   woutt = (u16*)(wsp + 65536 + 884736);                 // [384][384]
    float* bqkvp = (float*)(wsp + 65536 + 884736 + 294912);      // [1152]
    u16*   xb    = (u16*)(wsp + 65536 + 884736 + 294912 + 4608); // full 38.5MB
    const size_t fixed = 65536 + 884736 + 294912 + 4608
                       + (size_t)TOTROWS * DIM * 2;              // 39,784,960 B

    // per-batch chunk bytes: qkv (bf16) + att (bf16)
    const size_t perb = (size_t)ROWS_PER_B * (NQKV + DIM) * 2;   // 9,633,792
    int nb = 16;
    while (nb > 2 && fixed + (size_t)nb * perb > ws_size) nb >>= 1;

    u16* qkvb = xb + (size_t)TOTROWS * DIM;
    u16* attb = qkvb + (size_t)nb * ROWS_PER_B * NQKV;

    // ONE setup dispatch: cvt(full x) + emb4 + both weight transposes + bias
    setup_kernel<<<NB_SETUP, 256, 0, stream>>>(
        x, w_qkv, b_qkv, w_out, emb4, wqkvt, woutt, bqkvp, xb);

    for (int b0 = 0; b0 < 16; b0 += nb) {
        const int rows = nb * ROWS_PER_B;
        const u16* xa = xb + (size_t)b0 * ROWS_PER_B * DIM;

        mfma_gemm<0, NQKV, DIM><<<dim3(NQKV / 128, rows / 128), 512, 0, stream>>>(
            xa, wqkvt, bqkvp, qkvb, nullptr);

        attn_mfma_kernel<<<nb * 192, 256, 0, stream>>>(qkvb, emb4, attb);

        mfma_gemm<1, DIM, DIM><<<dim3(DIM / 128, rows / 128), 512, 0, stream>>>(
            attb, woutt, b_out, nullptr, out + (size_t)b0 * ROWS_PER_B * DIM);
    }
}